// Round 13
// baseline (277.428 us; speedup 1.0000x reference)
//
#include <hip/hip_runtime.h>
#include <hip/hip_bf16.h>

// RelativeAttention B=2,N=1024,C=512,H=8,HD=64 — round 12: global_load_lds attn.
//  m97 2-phase pattern: rpb staged HBM->LDS as f32 via global_load_lds (no
//  VGPR round-trip), converted LDS->LDS to padded bf16 tile at iter top.
//  kh/vt also gll tiles (kh source-XOR-swizzled, m173). In-loop VMEM = the
//  gll batch only, consumed with counted waits vmcnt(10)/(8); vmcnt(0) once
//  per iter at the end (next strip flew under the whole compute phase).
//  grid 256 = b(2) x itile(64) x jsplit(2); 1 block/CU; LDS 156.2KB.
// ws: qh 2MB | kh 2MB | vhT 2MB | xpart 8MB | lsum 128KB | xb 4MB

typedef __attribute__((ext_vector_type(8))) short short8;
typedef __attribute__((ext_vector_type(4))) short short4v;
typedef __attribute__((ext_vector_type(4))) float f32x4;

#if defined(__has_builtin)
#  if __has_builtin(__builtin_amdgcn_mfma_f32_16x16x16bf16_1k)
#    define HAVE_MFMA16 1
#  endif
#endif
#ifndef HAVE_MFMA16
#  define HAVE_MFMA16 0
#endif

__device__ __forceinline__ unsigned short f2b(float f) {
    union { float f; unsigned u; } v; v.f = f;
    unsigned r = (v.u + 0x7FFF + ((v.u >> 16) & 1)) >> 16;   // RNE
    return (unsigned short)r;
}

__device__ __forceinline__ unsigned cvt_pk(float a, float b) {
    unsigned r;
    asm("v_cvt_pk_bf16_f32 %0, %1, %2" : "=v"(r) : "v"(a), "v"(b));
    return r;
}

// lgkm-drain + raw barrier: LDS ordered; global loads NOT drained.
#define LGKM0_BAR()                                            \
    do {                                                       \
        asm volatile("s_waitcnt lgkmcnt(0)" ::: "memory");     \
        __builtin_amdgcn_s_barrier();                          \
        asm volatile("" ::: "memory");                         \
    } while (0)

__device__ __forceinline__ void gll16(const void* g, void* l) {
    __builtin_amdgcn_global_load_lds(
        (const __attribute__((address_space(1))) void*)g,
        (__attribute__((address_space(3))) void*)l, 16, 0, 0);
}

// ---------------------------------------------------------------------------
// GEMM: Y = X[2048,512] @ W[512,512]   (unchanged)
// ---------------------------------------------------------------------------
template <int MODE>
__global__ __launch_bounds__(256) void gemm512(
    const float* __restrict__ X, const float* __restrict__ W,
    const float* __restrict__ bias, float* __restrict__ Yf,
    unsigned short* __restrict__ Ybf, float scale)
{
    __shared__ float As[32][68];
    __shared__ float Bs[32][68];
    __shared__ float Ts[(MODE == 2) ? 64 : 1][65];
    const int t  = threadIdx.x;
    const int tx = t & 15, ty = t >> 4;
    const int m0 = blockIdx.x * 64;
    const int n0 = blockIdx.y * 64;

    float acc[4][4] = {};

    for (int k0 = 0; k0 < 512; k0 += 32) {
        #pragma unroll
        for (int l = 0; l < 2; l++) {
            int qi = t + l * 256;
            int r = qi >> 3, q = qi & 7;
            float4 av = *reinterpret_cast<const float4*>(
                X + (size_t)(m0 + r) * 512 + k0 + q * 4);
            As[q * 4 + 0][r] = av.x; As[q * 4 + 1][r] = av.y;
            As[q * 4 + 2][r] = av.z; As[q * 4 + 3][r] = av.w;
        }
        #pragma unroll
        for (int l = 0; l < 2; l++) {
            int qi = t + l * 256;
            int kk = qi >> 4, q = qi & 15;
            *reinterpret_cast<float4*>(&Bs[kk][q * 4]) =
                *reinterpret_cast<const float4*>(
                    W + (size_t)(k0 + kk) * 512 + n0 + q * 4);
        }
        __syncthreads();
        #pragma unroll
        for (int kk = 0; kk < 32; kk++) {
            float4 a4 = *reinterpret_cast<const float4*>(&As[kk][ty * 4]);
            float4 b4 = *reinterpret_cast<const float4*>(&Bs[kk][tx * 4]);
            float av[4] = {a4.x, a4.y, a4.z, a4.w};
            float bv[4] = {b4.x, b4.y, b4.z, b4.w};
            #pragma unroll
            for (int ii = 0; ii < 4; ii++)
                #pragma unroll
                for (int jj = 0; jj < 4; jj++)
                    acc[ii][jj] = fmaf(av[ii], bv[jj], acc[ii][jj]);
        }
        __syncthreads();
    }

    if (MODE == 0) {
        const int h = n0 >> 6;
        #pragma unroll
        for (int ii = 0; ii < 4; ii++) {
            int m = m0 + ty * 4 + ii;
            int bb = m >> 10, nn = m & 1023;
            ushort4 o;
            o.x = f2b(acc[ii][0] * scale); o.y = f2b(acc[ii][1] * scale);
            o.z = f2b(acc[ii][2] * scale); o.w = f2b(acc[ii][3] * scale);
            *reinterpret_cast<ushort4*>(
                Ybf + ((size_t)((bb * 8 + h) * 1024 + nn)) * 64 + tx * 4) = o;
        }
    } else if (MODE == 1) {
        float4 bv = *reinterpret_cast<const float4*>(bias + n0 + tx * 4);
        #pragma unroll
        for (int ii = 0; ii < 4; ii++) {
            int m = m0 + ty * 4 + ii;
            float4 o;
            o.x = acc[ii][0] + bv.x; o.y = acc[ii][1] + bv.y;
            o.z = acc[ii][2] + bv.z; o.w = acc[ii][3] + bv.w;
            *reinterpret_cast<float4*>(Yf + (size_t)m * 512 + n0 + tx * 4) = o;
        }
    } else {
        #pragma unroll
        for (int ii = 0; ii < 4; ii++)
            #pragma unroll
            for (int jj = 0; jj < 4; jj++)
                Ts[ty * 4 + ii][tx * 4 + jj] = acc[ii][jj];
        __syncthreads();
        const int h = n0 >> 6;
        const int bb = m0 >> 10, nn = m0 & 1023;
        const int rc = t >> 2, jc = t & 3;
        unsigned short tmp[16];
        #pragma unroll
        for (int q = 0; q < 16; q++) tmp[q] = f2b(Ts[jc * 16 + q][rc]);
        unsigned short* dst = Ybf + (((size_t)(bb * 8 + h) * 64 + rc) << 10) + nn + jc * 16;
        *reinterpret_cast<short8*>(dst)     = *reinterpret_cast<short8*>(&tmp[0]);
        *reinterpret_cast<short8*>(dst + 8) = *reinterpret_cast<short8*>(&tmp[8]);
    }
}

// ---------------------------------------------------------------------------
// attn: grid 256 = b(2) x itile(64) x jsplit(2); 512 thr = 8 waves = heads
// ---------------------------------------------------------------------------
__global__ __launch_bounds__(512, 2) void attn_mfma(
    const unsigned short* __restrict__ qhg, const unsigned short* __restrict__ khg,
    const unsigned short* __restrict__ vtg, const float* __restrict__ rpb,
    const float* __restrict__ mask, float* __restrict__ xpart,
    float* __restrict__ lsump)
{
    __shared__ float strip[16 * 16 * 64];            // 65536B f32 gll target
    __shared__ unsigned short rpb16[16][16][72];     // 36864B padded bf16 tile
    __shared__ unsigned short khs[8 * 16 * 64];      // 16384B linear, src-swz
    __shared__ unsigned short vts[8 * 64 * 16];      // 16384B linear [h][c][j]
    __shared__ unsigned short P[8][16][40];          // 10240B j16..39 ZERO
    __shared__ float S2s[16][8][17];                 //  8704B
    __shared__ float mask_s[512];                    //  2048B   total 156160B

    const int bid = blockIdx.x;
    const int js = bid & 1, it = (bid >> 1) & 63, b = bid >> 7;
    const int i0 = it * 16, jb = js * 512;
    const int t = threadIdx.x, w = t >> 6, l = t & 63;
    const int lg = l >> 4, l16 = l & 15;

    const float* rpbb = rpb + ((size_t)(b * 1024 + i0) << 16);

    // ---- gll batch macros (per-thread counts: kh 2, vt 2, strip 8) ----
#define KH_GLL(J0)                                                             \
    _Pragma("unroll")                                                          \
    for (int g = 0; g < 2; ++g) {                                              \
        int j_ = 8 * g + (l >> 3);                                             \
        int ck_ = (l & 7) ^ (j_ & 7);                                          \
        gll16(khg + ((size_t)(b * 8 + w) << 16) + (size_t)((J0) + j_) * 64 + ck_ * 8, \
              (char*)khs + (w * 2 + g) * 1024);                                \
    }
#define VT_GLL(J0)                                                             \
    _Pragma("unroll")                                                          \
    for (int g = 0; g < 2; ++g) {                                              \
        int Lb_ = (w * 2 + g) * 1024 + l * 16;                                 \
        int c_ = (Lb_ & 2047) >> 5;                                            \
        int ch_ = (Lb_ >> 4) & 1;                                              \
        gll16(vtg + ((size_t)(b * 8 + w) << 16) + ((size_t)c_ << 10) + (J0) + ch_ * 8, \
              (char*)vts + (w * 2 + g) * 1024);                                \
    }
#define STRIP_GLL(J0)                                                          \
    _Pragma("unroll")                                                          \
    for (int g = 0; g < 8; ++g) {                                              \
        int Lb_ = (w * 8 + g) * 1024 + l * 16;                                 \
        int ii_ = Lb_ >> 12;                                                   \
        int of_ = Lb_ & 4095;                                                  \
        gll16(rpbb + ((size_t)ii_ << 16) + (size_t)(J0) * 64 + (of_ >> 2),     \
              (char*)strip + (w * 8 + g) * 1024);                              \
    }

    // ---- prologue: q staged into strip alias; mask; zero P ----
    {
        unsigned short (*q1)[16][72] = (unsigned short (*)[16][72])strip;
        {
            int h = t >> 6, i = (t >> 2) & 15, c = (t & 3) * 16;
            const short8* src = reinterpret_cast<const short8*>(
                qhg + (((size_t)(b * 8 + h) * 1024 + i0 + i) << 6) + c);
            *reinterpret_cast<short8*>(&q1[h][i][c])     = src[0];
            *reinterpret_cast<short8*>(&q1[h][i][c + 8]) = src[1];
        }
        if (t < 128) {
            *reinterpret_cast<float4*>(&mask_s[t * 4]) =
                *reinterpret_cast<const float4*>(&mask[b * 1024 + jb + t * 4]);
        }
        {
            unsigned short* P1 = &P[0][0][0];
            #pragma unroll
            for (int r = 0; r < 10; ++r) P1[t + 512 * r] = 0;   // 5120
        }
        __syncthreads();
        // hoist loop-invariant q fragments, then free the alias
        goto after_q;   // (placeholder removed below; fragments read here)
    after_q:;
    }
    unsigned short (*q1a)[16][72] = (unsigned short (*)[16][72])strip;
    short8 a1[2];
    a1[0] = *reinterpret_cast<const short8*>(&q1a[w][l16][8 * lg]);
    a1[1] = *reinterpret_cast<const short8*>(&q1a[w][l16][32 + 8 * lg]);
    short8 bq[2][2];
    #pragma unroll
    for (int il = 0; il < 2; ++il) {
        bq[il][0] = *reinterpret_cast<const short8*>(
            &q1a[l16 & 7][2 * w + il][8 * lg]);
        bq[il][1] = *reinterpret_cast<const short8*>(
            &q1a[l16 & 7][2 * w + il][32 + 8 * lg]);
    }
    float mrow[4];
    #pragma unroll
    for (int r = 0; r < 4; r++) mrow[r] = mask[b * 1024 + i0 + lg * 4 + r];

    __syncthreads();                 // all q reads done; strip free for gll
    STRIP_GLL(jb)                    // tile 0 -> strip
    asm volatile("s_waitcnt vmcnt(0)" ::: "memory");
    __syncthreads();                 // strip(0) landed everywhere

    const int jo = (lg < 2) ? 8 * lg : 0;   // K32-fallback zero-pad clamp
    const int ro = jo;
    (void)ro;

    f32x4 x1[4];
    #pragma unroll
    for (int cs = 0; cs < 4; cs++) x1[cs] = 0.0f;
    f32x4 x2[2][4];
    #pragma unroll
    for (int il = 0; il < 2; il++)
        #pragma unroll
        for (int cg = 0; cg < 4; cg++) x2[il][cg] = 0.0f;
    float lsum[4] = {0.f, 0.f, 0.f, 0.f};

    for (int jt = 0; jt < 32; ++jt) {
        const int j0 = jb + jt * 16;

        // ---- phase 0: convert strip(jt) f32 -> rpb16 (padded bf16) ----
        #pragma unroll
        for (int k = 0; k < 8; ++k) {
            int f = k * 512 + t;
            float4 v4 = *reinterpret_cast<const float4*>(&strip[f * 4]);
            int e = f * 4;
            int ii = e >> 10, jj = (e >> 6) & 15, cc = e & 63;
            uint2 pk;
            pk.x = cvt_pk(v4.x, v4.y);
            pk.y = cvt_pk(v4.z, v4.w);
            *reinterpret_cast<uint2*>(&rpb16[ii][jj][cc]) = pk;
        }
        LGKM0_BAR();   // bar1: rpb16 visible; strip free; khs/vts readers done

        // ---- issue gll batch: kh(jt), vt(jt), strip(jt+1) ----
        KH_GLL(j0)
        VT_GLL(j0)
        if (jt < 31) { STRIP_GLL(j0 + 16) }

        // ---- phase 1: S2^T = rpb(A) @ q(B) : D[16j x 8h] per i ----
        #pragma unroll
        for (int il = 0; il < 2; ++il) {
            int i = 2 * w + il;
            f32x4 D2; D2 = 0.0f;
            #pragma unroll
            for (int ch = 0; ch < 2; ++ch) {
                short8 ar = *reinterpret_cast<const short8*>(
                    &rpb16[i][l16][ch * 32 + 8 * lg]);
                D2 = __builtin_amdgcn_mfma_f32_16x16x32_bf16(ar, bq[il][ch], D2, 0, 0, 0);
            }
            if (l16 < 8) {
                #pragma unroll
                for (int r = 0; r < 4; ++r)
                    S2s[i][l16][4 * lg + r] = D2[r];
            }
        }
        LGKM0_BAR();   // bar2: S2s ready

        // ---- phase 2: S1 (khs, counted wait) + P = exp(...) ----
        asm volatile("s_waitcnt vmcnt(10)" ::: "memory");   // kh landed
        __builtin_amdgcn_sched_barrier(0);
        f32x4 C1; C1 = 0.0f;
        {
            int c0 = lg ^ (l16 & 7);
            int c1 = (4 + lg) ^ (l16 & 7);
            short8 kb0 = *reinterpret_cast<const short8*>(
                (char*)khs + w * 2048 + l16 * 128 + c0 * 16);
            short8 kb1 = *reinterpret_cast<const short8*>(
                (char*)khs + w * 2048 + l16 * 128 + c1 * 16);
            C1 = __builtin_amdgcn_mfma_f32_16x16x32_bf16(a1[0], kb0, C1, 0, 0, 0);
            C1 = __builtin_amdgcn_mfma_f32_16x16x32_bf16(a1[1], kb1, C1, 0, 0, 0);
        }
        {
            float mj = mask_s[jt * 16 + l16];
            #pragma unroll
            for (int r = 0; r < 4; ++r) {
                int ir = lg * 4 + r;
                float mi = mrow[r];
                float pm = (fmaxf(mi, mj) < 0.f) ? 0.f : fminf(mi, mj);
                float s = C1[r] + S2s[ir][w][l16] + pm;
                float p = __expf(s);              // bounded logits; -1e4 -> 0
                lsum[r] += p;
                P[w][ir][l16] = f2b(p);
            }
        }
        LGKM0_BAR();   // bar3: P ready

        // ---- phase 3: X1 (vts, counted wait) + X2 (rpb16) ----
        asm volatile("s_waitcnt vmcnt(8)" ::: "memory");    // vt landed
        __builtin_amdgcn_sched_barrier(0);
#if HAVE_MFMA16
        {
            short4v pa = *reinterpret_cast<const short4v*>(&P[w][l16][4 * lg]);
            #pragma unroll
            for (int cs = 0; cs < 4; ++cs) {
                short4v vb = *reinterpret_cast<const short4v*>(
                    (char*)vts + w * 2048 + (cs * 16 + l16) * 32 + lg * 8);
                x1[cs] = __builtin_amdgcn_mfma_f32_16x16x16bf16_1k(pa, vb, x1[cs], 0, 0, 0);
            }
        }
        #pragma unroll
        for (int il = 0; il < 2; ++il) {
            int i = 2 * w + il;
            short4v pa2 = *reinterpret_cast<const short4v*>(&P[l16 & 7][i][4 * lg]);
            #pragma unroll
            for (int cg = 0; cg < 4; ++cg) {
                short4v bb;
                #pragma unroll
                for (int e = 0; e < 4; ++e)
                    bb[e] = (short)rpb16[i][4 * lg + e][cg * 16 + l16];
                x2[il][cg] = __builtin_amdgcn_mfma_f32_16x16x16bf16_1k(pa2, bb, x2[il][cg], 0, 0, 0);
            }
        }
#else
        {
            short8 pa = *reinterpret_cast<const short8*>(&P[w][l16][8 * lg]);
            #pragma unroll
            for (int cs = 0; cs < 4; ++cs) {
                short8 vb = *reinterpret_cast<const short8*>(
                    (char*)vts + w * 2048 + (cs * 16 + l16) * 32 + jo * 2);
                x1[cs] = __builtin_amdgcn_mfma_f32_16x16x32_bf16(pa, vb, x1[cs], 0, 0, 0);
            }
        }
        #pragma unroll
        for (int il = 0; il < 2; ++il) {
            int i = 2 * w + il;
            short8 pa2 = *reinterpret_cast<const short8*>(&P[l16 & 7][i][8 * lg]);
            #pragma unroll
            for (int cg = 0; cg < 4; ++cg) {
                short8 bb;
                #pragma unroll
                for (int e = 0; e < 8; ++e)
                    bb[e] = (short)rpb16[i][ro + e][cg * 16 + l16];
                x2[il][cg] = __builtin_amdgcn_mfma_f32_16x16x32_bf16(pa2, bb, x2[il][cg], 0, 0, 0);
            }
        }
#endif
        // ---- end: strip(jt+1) landed (flew under whole compute) ----
        asm volatile("s_waitcnt vmcnt(0)" ::: "memory");
        LGKM0_BAR();   // bar4
    }

    // ---- epilogue ----
    #pragma unroll
    for (int r = 0; r < 4; ++r) {
        float v = lsum[r];
        v += __shfl_xor(v, 1, 64); v += __shfl_xor(v, 2, 64);
        v += __shfl_xor(v, 4, 64); v += __shfl_xor(v, 8, 64);
        lsum[r] = v;
    }

    __syncthreads();
    float* x2s = strip;   // [16i][8h][64c] f32 (32KB of the 64KB strip)
    if (lg < 2) {
        #pragma unroll
        for (int il = 0; il < 2; ++il)
            #pragma unroll
            for (int cg = 0; cg < 4; ++cg)
                #pragma unroll
                for (int r = 0; r < 4; ++r)
                    x2s[((2 * w + il) * 8 + 4 * lg + r) * 64 + cg * 16 + l16] =
                        x2[il][cg][r];
    }
    __syncthreads();

    #pragma unroll
    for (int cs = 0; cs < 4; ++cs)
        #pragma unroll
        for (int r = 0; r < 4; ++r) {
            int ir = lg * 4 + r;
            float val = x1[cs][r] + x2s[(ir * 8 + w) * 64 + cs * 16 + l16];
            xpart[((size_t)js << 20) + ((size_t)(b * 1024 + i0 + ir)) * 512
                  + w * 64 + cs * 16 + l16] = val;
        }
    if (l16 == 0) {
        #pragma unroll
        for (int r = 0; r < 4; ++r)
            lsump[((size_t)js << 14) + (b * 8 + w) * 1024 + i0 + lg * 4 + r] = lsum[r];
    }
#undef KH_GLL
#undef VT_GLL
#undef STRIP_GLL
}

// ---------------------------------------------------------------------------
__global__ __launch_bounds__(256) void combine(
    const float* __restrict__ xpart, const float* __restrict__ lsump,
    float* __restrict__ xb)
{
    int idx4 = blockIdx.x * 256 + threadIdx.x;
    size_t base = (size_t)idx4 * 4;
    int row = (int)(base >> 9), col = (int)(base & 511);
    int bb = row >> 10, n = row & 1023, h = col >> 6;
    float ax = 0.f, ay = 0.f, az = 0.f, aw = 0.f, ls = 0.f;
    #pragma unroll
    for (int js = 0; js < 2; ++js) {
        float4 v = *reinterpret_cast<const float4*>(xpart + ((size_t)js << 20) + base);
        ax += v.x; ay += v.y; az += v.z; aw += v.w;
        ls += lsump[(js << 14) + (bb * 8 + h) * 1024 + n];
    }
    float inv = 1.f / ls;
    float4 o; o.x = ax * inv; o.y = ay * inv; o.z = az * inv; o.w = aw * inv;
    *reinterpret_cast<float4*>(xb + base) = o;
}

// ---------------------------------------------------------------------------
extern "C" void kernel_launch(void* const* d_in, const int* in_sizes, int n_in,
                              void* d_out, int out_size, void* d_ws, size_t ws_size,
                              hipStream_t stream)
{
    (void)in_sizes; (void)n_in; (void)out_size; (void)ws_size;
    const float* q    = (const float*)d_in[0];
    const float* k    = (const float*)d_in[1];
    const float* v    = (const float*)d_in[2];
    const float* rpb  = (const float*)d_in[3];
    const float* mask = (const float*)d_in[4];
    const float* Wq   = (const float*)d_in[5];
    const float* Wk   = (const float*)d_in[6];
    const float* Wv   = (const float*)d_in[7];
    const float* Wp   = (const float*)d_in[8];
    const float* bp   = (const float*)d_in[9];
    float* out = (float*)d_out;

    unsigned short* qhb = (unsigned short*)d_ws;     // bf16 [2,8,1024,64]
    unsigned short* khb = qhb + 1048576;
    unsigned short* vtb = khb + 1048576;             // bf16 [2,8,64,1024]
    float* xpart = (float*)(vtb + 1048576);          // [2][2048][512]
    float* lsump = xpart + 2097152;                  // [2][16384]
    float* xb    = lsump + 32768;                    // [2048][512]

    dim3 gg(32, 8, 1);
    gemm512<0><<<gg, 256, 0, stream>>>(q, Wq, nullptr, nullptr, qhb, 0.125f);
    gemm512<0><<<gg, 256, 0, stream>>>(k, Wk, nullptr, nullptr, khb, 1.0f);
    gemm512<2><<<gg, 256, 0, stream>>>(v, Wv, nullptr, nullptr, vtb, 1.0f);

    attn_mfma<<<256, 512, 0, stream>>>(qhb, khb, vtb, rpb, mask, xpart, lsump);

    combine<<<1024, 256, 0, stream>>>(xpart, lsump, xb);

    gemm512<1><<<gg, 256, 0, stream>>>(xb, Wp, bp, out, nullptr, 1.0f);
}

// Round 14
// 189.172 us; speedup vs baseline: 1.4665x; 1.4665x over previous
//
#include <hip/hip_runtime.h>
#include <hip/hip_bf16.h>

// RelativeAttention B=2,N=1024,C=512,H=8,HD=64 — round 13: MFMA projections.
//  attn = round-11 kernel VERBATIM (best: 257.5us total).
//  NEW: wprep transposes Wq/Wk/Wv -> bf16 WT[n][k] (L2-hot B-frags);
//       proj_mfma (one launch, z = q/k/v) does the three projections with
//       mfma_f32_16x16x32_bf16, f32 accum, bit-compatible scatter epilogues.
//  Final GEMM stays f32 (precision margin); combine unchanged.
// ws: qh 2MB | kh 2MB | vhT 2MB | xpart 8MB | lsum 128KB | xb 4MB | WT 1.5MB

typedef __attribute__((ext_vector_type(8))) short short8;
typedef __attribute__((ext_vector_type(4))) short short4v;
typedef __attribute__((ext_vector_type(4))) float f32x4;

#if defined(__has_builtin)
#  if __has_builtin(__builtin_amdgcn_mfma_f32_16x16x16bf16_1k)
#    define HAVE_MFMA16 1
#  endif
#endif
#ifndef HAVE_MFMA16
#  define HAVE_MFMA16 0
#endif

__device__ __forceinline__ unsigned short f2b(float f) {
    union { float f; unsigned u; } v; v.f = f;
    unsigned r = (v.u + 0x7FFF + ((v.u >> 16) & 1)) >> 16;   // RNE
    return (unsigned short)r;
}

__device__ __forceinline__ unsigned cvt_pk(float a, float b) {
    unsigned r;
    asm("v_cvt_pk_bf16_f32 %0, %1, %2" : "=v"(r) : "v"(a), "v"(b));
    return r;
}

// lgkm-drain + raw barrier: LDS ordered; global loads NOT drained.
#define LGKM0_BAR()                                            \
    do {                                                       \
        asm volatile("s_waitcnt lgkmcnt(0)" ::: "memory");     \
        __builtin_amdgcn_s_barrier();                          \
        asm volatile("" ::: "memory");                         \
    } while (0)

// ---------------------------------------------------------------------------
// wprep: W f32 [k][n] -> WT bf16 [n][k]  (Wq, Wk, Wv; grid z = 0..2)
// ---------------------------------------------------------------------------
__global__ __launch_bounds__(256) void wprep(
    const float* __restrict__ W0, const float* __restrict__ W1,
    const float* __restrict__ W2, unsigned short* __restrict__ WT)
{
    const int z = blockIdx.z;
    const float* W = (z == 0) ? W0 : ((z == 1) ? W1 : W2);
    unsigned short* T = WT + (size_t)z * 262144;
    __shared__ float Ts[64][65];
    const int t = threadIdx.x;
    const int k0 = blockIdx.x * 64, n0 = blockIdx.y * 64;
    const int kr = t >> 2, nc = (t & 3) * 16;
    #pragma unroll
    for (int q = 0; q < 4; ++q) {
        float4 v = *reinterpret_cast<const float4*>(
            W + (size_t)(k0 + kr) * 512 + n0 + nc + q * 4);
        Ts[kr][nc + q * 4 + 0] = v.x; Ts[kr][nc + q * 4 + 1] = v.y;
        Ts[kr][nc + q * 4 + 2] = v.z; Ts[kr][nc + q * 4 + 3] = v.w;
    }
    __syncthreads();
    const int nl = t >> 2, kc = (t & 3) * 16;
    unsigned short tmp[16];
    #pragma unroll
    for (int e = 0; e < 16; ++e) tmp[e] = f2b(Ts[kc + e][nl]);
    unsigned short* dst = T + (size_t)(n0 + nl) * 512 + k0 + kc;
    *reinterpret_cast<short8*>(dst)     = *reinterpret_cast<short8*>(&tmp[0]);
    *reinterpret_cast<short8*>(dst + 8) = *reinterpret_cast<short8*>(&tmp[8]);
}

// ---------------------------------------------------------------------------
// proj_mfma: Y = X[2048,512] @ W  (bf16 MFMA, f32 acc); z=0 q(scale) z=1 k
// z=2 v (transposed scatter). grid (32, 8, 3), 256 thr = 4 waves.
// ---------------------------------------------------------------------------
__global__ __launch_bounds__(256) void proj_mfma(
    const float* __restrict__ qg, const float* __restrict__ kg,
    const float* __restrict__ vg, const unsigned short* __restrict__ WT,
    unsigned short* __restrict__ qhb, unsigned short* __restrict__ khb,
    unsigned short* __restrict__ vtb)
{
    const int z = blockIdx.z;
    const float* X = (z == 0) ? qg : ((z == 1) ? kg : vg);
    const unsigned short* WTz = WT + (size_t)z * 262144;
    const float scale = (z == 0) ? 0.125f : 1.0f;

    __shared__ unsigned short As[64][72];
    const int t = threadIdx.x, w = t >> 6, l = t & 63;
    const int l16 = l & 15, lg = l >> 4;
    const int m0 = blockIdx.x * 64, n0 = blockIdx.y * 64;
    const int ra = t >> 2, kc = (t & 3) * 16;

    f32x4 acc[4];
    #pragma unroll
    for (int cs = 0; cs < 4; ++cs) acc[cs] = 0.0f;

    for (int k0 = 0; k0 < 512; k0 += 64) {
        float4 va[4];
        #pragma unroll
        for (int qq = 0; qq < 4; ++qq)
            va[qq] = *reinterpret_cast<const float4*>(
                X + (size_t)(m0 + ra) * 512 + k0 + kc + qq * 4);
        uint4 pk0, pk1;
        pk0.x = cvt_pk(va[0].x, va[0].y); pk0.y = cvt_pk(va[0].z, va[0].w);
        pk0.z = cvt_pk(va[1].x, va[1].y); pk0.w = cvt_pk(va[1].z, va[1].w);
        pk1.x = cvt_pk(va[2].x, va[2].y); pk1.y = cvt_pk(va[2].z, va[2].w);
        pk1.z = cvt_pk(va[3].x, va[3].y); pk1.w = cvt_pk(va[3].z, va[3].w);
        __syncthreads();                       // prev-iter readers done
        *reinterpret_cast<uint4*>(&As[ra][kc])     = pk0;
        *reinterpret_cast<uint4*>(&As[ra][kc + 8]) = pk1;
        __syncthreads();                       // tile staged
        #pragma unroll
        for (int kk = 0; kk < 2; ++kk) {
            short8 a = *reinterpret_cast<const short8*>(
                &As[w * 16 + l16][kk * 32 + 8 * lg]);
            #pragma unroll
            for (int cs = 0; cs < 4; ++cs) {
                short8 b = *reinterpret_cast<const short8*>(
                    WTz + (size_t)(n0 + cs * 16 + l16) * 512 + k0 + kk * 32 + 8 * lg);
                acc[cs] = __builtin_amdgcn_mfma_f32_16x16x32_bf16(a, b, acc[cs], 0, 0, 0);
            }
        }
    }

    const int h = blockIdx.y;                  // n0 >> 6
    if (z < 2) {
        unsigned short* Y = (z == 0) ? qhb : khb;
        #pragma unroll
        for (int cs = 0; cs < 4; ++cs)
            #pragma unroll
            for (int r = 0; r < 4; ++r) {
                int m = m0 + w * 16 + lg * 4 + r;
                int bb = m >> 10, nn = m & 1023;
                Y[(((size_t)((bb * 8 + h) * 1024 + nn)) << 6) + cs * 16 + l16] =
                    f2b(acc[cs][r] * scale);
            }
    } else {
        int mbase = m0 + w * 16 + lg * 4;
        int bb = mbase >> 10, nn = mbase & 1023;
        #pragma unroll
        for (int cs = 0; cs < 4; ++cs) {
            ushort4 o;
            o.x = f2b(acc[cs][0]); o.y = f2b(acc[cs][1]);
            o.z = f2b(acc[cs][2]); o.w = f2b(acc[cs][3]);
            *reinterpret_cast<ushort4*>(
                vtb + (((size_t)(bb * 8 + h) * 64 + cs * 16 + l16) << 10) + nn) = o;
        }
    }
}

// ---------------------------------------------------------------------------
// GEMM (f32 VALU) — used only for the final out = xb @ Wp + bp (MODE 1)
// ---------------------------------------------------------------------------
template <int MODE>
__global__ __launch_bounds__(256) void gemm512(
    const float* __restrict__ X, const float* __restrict__ W,
    const float* __restrict__ bias, float* __restrict__ Yf,
    unsigned short* __restrict__ Ybf, float scale)
{
    __shared__ float As[32][68];
    __shared__ float Bs[32][68];
    const int t  = threadIdx.x;
    const int tx = t & 15, ty = t >> 4;
    const int m0 = blockIdx.x * 64;
    const int n0 = blockIdx.y * 64;

    float acc[4][4] = {};

    for (int k0 = 0; k0 < 512; k0 += 32) {
        #pragma unroll
        for (int l = 0; l < 2; l++) {
            int qi = t + l * 256;
            int r = qi >> 3, q = qi & 7;
            float4 av = *reinterpret_cast<const float4*>(
                X + (size_t)(m0 + r) * 512 + k0 + q * 4);
            As[q * 4 + 0][r] = av.x; As[q * 4 + 1][r] = av.y;
            As[q * 4 + 2][r] = av.z; As[q * 4 + 3][r] = av.w;
        }
        #pragma unroll
        for (int l = 0; l < 2; l++) {
            int qi = t + l * 256;
            int kk = qi >> 4, q = qi & 15;
            *reinterpret_cast<float4*>(&Bs[kk][q * 4]) =
                *reinterpret_cast<const float4*>(
                    W + (size_t)(k0 + kk) * 512 + n0 + q * 4);
        }
        __syncthreads();
        #pragma unroll
        for (int kk = 0; kk < 32; kk++) {
            float4 a4 = *reinterpret_cast<const float4*>(&As[kk][ty * 4]);
            float4 b4 = *reinterpret_cast<const float4*>(&Bs[kk][tx * 4]);
            float av[4] = {a4.x, a4.y, a4.z, a4.w};
            float bv[4] = {b4.x, b4.y, b4.z, b4.w};
            #pragma unroll
            for (int ii = 0; ii < 4; ii++)
                #pragma unroll
                for (int jj = 0; jj < 4; jj++)
                    acc[ii][jj] = fmaf(av[ii], bv[jj], acc[ii][jj]);
        }
        __syncthreads();
    }

    float4 bv = *reinterpret_cast<const float4*>(bias + n0 + tx * 4);
    #pragma unroll
    for (int ii = 0; ii < 4; ii++) {
        int m = m0 + ty * 4 + ii;
        float4 o;
        o.x = acc[ii][0] + bv.x; o.y = acc[ii][1] + bv.y;
        o.z = acc[ii][2] + bv.z; o.w = acc[ii][3] + bv.w;
        *reinterpret_cast<float4*>(Yf + (size_t)m * 512 + n0 + tx * 4) = o;
    }
    (void)Ybf; (void)scale;
}

// ---------------------------------------------------------------------------
// attn: round-11 kernel VERBATIM.
// grid 256 = b(2) x itile(64) x jsplit(2); 512 thr = 8 waves = heads
// ---------------------------------------------------------------------------
__global__ __launch_bounds__(512, 2) void attn_mfma(
    const unsigned short* __restrict__ qhg, const unsigned short* __restrict__ khg,
    const unsigned short* __restrict__ vtg, const float* __restrict__ rpb,
    const float* __restrict__ mask, float* __restrict__ xpart,
    float* __restrict__ lsump)
{
    __shared__ unsigned short rpb_s[2][16][16][72]; // dbuf rpb tile   73728B
    __shared__ unsigned short khs[8][16][72];       // kh tile [h][j][c] 18432B
    __shared__ unsigned short vts[8][64][24];       // vt tile [h][c][j] 24576B
    __shared__ unsigned short q1[8][16][72];        // prologue q       18432B
    __shared__ unsigned short P[8][16][40];         // j16..39 ZERO     10240B
    __shared__ float S2s[16][8][17];                //                   8704B
    __shared__ float mask_s[512];                   //                   2048B

    const int bid = blockIdx.x;
    const int js = bid & 1, it = (bid >> 1) & 63, b = bid >> 7;
    const int i0 = it * 16, jb = js * 512;
    const int t = threadIdx.x, w = t >> 6, l = t & 63;
    const int lg = l >> 4, l16 = l & 15;

    const int sj = (t >> 3) & 15, sc = (t & 7) * 8, sib = t >> 7;
    const int kh_h = t >> 6, kh_j = (t >> 2) & 15, kh_c = (t & 3) * 16;
    const int vt_h = t >> 6, vt_c = t & 63;

    const float* rpbb = rpb + ((size_t)(b * 1024 + i0) << 16);

#define RPB_ISSUE(PF, J0)                                                      \
    _Pragma("unroll")                                                          \
    for (int itr = 0; itr < 4; ++itr) {                                        \
        const float4* s_ = reinterpret_cast<const float4*>(                    \
            rpbb + ((size_t)(sib + 4 * itr) << 16) +                           \
            (size_t)((J0) + sj) * 64 + sc);                                    \
        PF[2 * itr] = s_[0]; PF[2 * itr + 1] = s_[1];                          \
    }

#define RPB_WRITE(PF, BUF)                                                     \
    _Pragma("unroll")                                                          \
    for (int itr = 0; itr < 4; ++itr) {                                        \
        float4 ua = PF[2 * itr], ub = PF[2 * itr + 1];                         \
        uint4 pk;                                                              \
        pk.x = cvt_pk(ua.x, ua.y); pk.y = cvt_pk(ua.z, ua.w);                  \
        pk.z = cvt_pk(ub.x, ub.y); pk.w = cvt_pk(ub.z, ub.w);                  \
        *reinterpret_cast<uint4*>(&rpb_s[BUF][sib + 4 * itr][sj][sc]) = pk;    \
    }

#define KH_ISSUE(KP, J0)                                                       \
    {                                                                          \
        const unsigned short* p_ = khg + ((size_t)(b * 8 + kh_h) << 16) +      \
            (size_t)((J0) + kh_j) * 64 + kh_c;                                 \
        KP[0] = *reinterpret_cast<const short8*>(p_);                          \
        KP[1] = *reinterpret_cast<const short8*>(p_ + 8);                      \
    }

#define KH_WRITE(KP)                                                           \
    {                                                                          \
        *reinterpret_cast<short8*>(&khs[kh_h][kh_j][kh_c])     = KP[0];        \
        *reinterpret_cast<short8*>(&khs[kh_h][kh_j][kh_c + 8]) = KP[1];        \
    }

#define VT_ISSUE(VP, J0)                                                       \
    {                                                                          \
        const unsigned short* p_ = vtg + ((size_t)(b * 8 + vt_h) << 16) +      \
            ((size_t)vt_c << 10) + (J0);                                       \
        VP[0] = *reinterpret_cast<const short8*>(p_);                          \
        VP[1] = *reinterpret_cast<const short8*>(p_ + 8);                      \
    }

#define VT_WRITE(VP)                                                           \
    {                                                                          \
        *reinterpret_cast<short8*>(&vts[vt_h][vt_c][0]) = VP[0];               \
        *reinterpret_cast<short8*>(&vts[vt_h][vt_c][8]) = VP[1];               \
    }

    {
        int h = t >> 6, i = (t >> 2) & 15, c = (t & 3) * 16;
        const short8* src = reinterpret_cast<const short8*>(
            qhg + (((size_t)(b * 8 + h) * 1024 + i0 + i) << 6) + c);
        *reinterpret_cast<short8*>(&q1[h][i][c])     = src[0];
        *reinterpret_cast<short8*>(&q1[h][i][c + 8]) = src[1];
    }
    if (t < 128) {
        *reinterpret_cast<float4*>(&mask_s[t * 4]) =
            *reinterpret_cast<const float4*>(&mask[b * 1024 + jb + t * 4]);
    }
    {
        unsigned short* P1 = &P[0][0][0];
        #pragma unroll
        for (int r = 0; r < 10; ++r) P1[t + 512 * r] = 0;   // 5120 = 512*10
    }
    float mrow[4];
    #pragma unroll
    for (int r = 0; r < 4; r++) mrow[r] = mask[b * 1024 + i0 + lg * 4 + r];

    float4 pfA[8], pfB[8];
    short8 kpfA[2], kpfB[2], vpfA[2], vpfB[2];
    RPB_ISSUE(pfA, jb)
    KH_ISSUE(kpfA, jb)
    VT_ISSUE(vpfA, jb)

    LGKM0_BAR();

    short8 a1[2];
    a1[0] = *reinterpret_cast<const short8*>(&q1[w][l16][8 * lg]);
    a1[1] = *reinterpret_cast<const short8*>(&q1[w][l16][32 + 8 * lg]);
    short8 bq[2][2];
    #pragma unroll
    for (int il = 0; il < 2; ++il) {
        bq[il][0] = *reinterpret_cast<const short8*>(
            &q1[l16 & 7][2 * w + il][8 * lg]);
        bq[il][1] = *reinterpret_cast<const short8*>(
            &q1[l16 & 7][2 * w + il][32 + 8 * lg]);
    }

    const int jo = (lg < 2) ? 8 * lg : 0;
    const int ro = jo;
    (void)ro;

    f32x4 x1[4];
    #pragma unroll
    for (int cs = 0; cs < 4; cs++) x1[cs] = 0.0f;
    f32x4 x2[2][4];
    #pragma unroll
    for (int il = 0; il < 2; il++)
        #pragma unroll
        for (int cg = 0; cg < 4; cg++) x2[il][cg] = 0.0f;
    float lsum[4] = {0.f, 0.f, 0.f, 0.f};

#define ATTN_ITER(T, PFC, KPC, VPC, PFN, KPN, VPN)                             \
    {                                                                          \
        const int jt = (T);                                                    \
        const int cur = jt & 1;                                                \
        const int j0 = jb + jt * 16;                                           \
        if (jt < 31) {                                                         \
            RPB_ISSUE(PFN, j0 + 16)                                            \
            KH_ISSUE(KPN, j0 + 16)                                             \
            VT_ISSUE(VPN, j0 + 16)                                             \
        }                                                                      \
        RPB_WRITE(PFC, cur)                                                    \
        KH_WRITE(KPC)                                                          \
        VT_WRITE(VPC)                                                          \
        LGKM0_BAR();                                                           \
        f32x4 C1; C1 = 0.0f;                                                   \
        {                                                                      \
            short8 kb0 = *reinterpret_cast<const short8*>(&khs[w][l16][8 * lg]); \
            short8 kb1 = *reinterpret_cast<const short8*>(&khs[w][l16][32 + 8 * lg]); \
            C1 = __builtin_amdgcn_mfma_f32_16x16x32_bf16(a1[0], kb0, C1, 0, 0, 0); \
            C1 = __builtin_amdgcn_mfma_f32_16x16x32_bf16(a1[1], kb1, C1, 0, 0, 0); \
        }                                                                      \
        _Pragma("unroll")                                                      \
        for (int il = 0; il < 2; ++il) {                                       \
            int i = 2 * w + il;                                                \
            f32x4 D2; D2 = 0.0f;                                               \
            _Pragma("unroll")                                                  \
            for (int ch = 0; ch < 2; ++ch) {                                   \
                short8 ar = *reinterpret_cast<const short8*>(                  \
                    &rpb_s[cur][i][l16][ch * 32 + 8 * lg]);                    \
                D2 = __builtin_amdgcn_mfma_f32_16x16x32_bf16(ar, bq[il][ch], D2, 0, 0, 0); \
            }                                                                  \
            if (l16 < 8) {                                                     \
                _Pragma("unroll")                                              \
                for (int r = 0; r < 4; ++r)                                    \
                    S2s[i][l16][4 * lg + r] = D2[r];                           \
            }                                                                  \
        }                                                                      \
        LGKM0_BAR();                                                           \
        {                                                                      \
            float mj = mask_s[jt * 16 + l16];                                  \
            _Pragma("unroll")                                                  \
            for (int r = 0; r < 4; ++r) {                                      \
                int ir = lg * 4 + r;                                           \
                float mi = mrow[r];                                            \
                float pm = (fmaxf(mi, mj) < 0.f) ? 0.f : fminf(mi, mj);        \
                float s = C1[r] + S2s[ir][w][l16] + pm;                        \
                float p = __expf(s);                                           \
                lsum[r] += p;                                                  \
                P[w][ir][l16] = f2b(p);                                        \
            }                                                                  \
        }                                                                      \
        LGKM0_BAR();                                                           \
        X1X2_BODY(cur)                                                         \
        LGKM0_BAR();                                                           \
    }

#if HAVE_MFMA16
#define X1X2_BODY(CUR)                                                         \
    {                                                                          \
        short4v pa = *reinterpret_cast<const short4v*>(&P[w][l16][4 * lg]);    \
        _Pragma("unroll")                                                      \
        for (int cs = 0; cs < 4; ++cs) {                                       \
            short4v vb = *reinterpret_cast<const short4v*>(                    \
                &vts[w][cs * 16 + l16][4 * lg]);                               \
            x1[cs] = __builtin_amdgcn_mfma_f32_16x16x16bf16_1k(pa, vb, x1[cs], 0, 0, 0); \
        }                                                                      \
    }                                                                          \
    _Pragma("unroll")                                                          \
    for (int il = 0; il < 2; ++il) {                                           \
        int i = 2 * w + il;                                                    \
        short4v pa2 = *reinterpret_cast<const short4v*>(&P[l16 & 7][i][4 * lg]); \
        _Pragma("unroll")                                                      \
        for (int cg = 0; cg < 4; ++cg) {                                       \
            short4v bb;                                                        \
            _Pragma("unroll")                                                  \
            for (int e = 0; e < 4; ++e)                                        \
                bb[e] = (short)rpb_s[CUR][i][4 * lg + e][cg * 16 + l16];       \
            x2[il][cg] = __builtin_amdgcn_mfma_f32_16x16x16bf16_1k(pa2, bb, x2[il][cg], 0, 0, 0); \
        }                                                                      \
    }
#else
#define X1X2_BODY(CUR)                                                         \
    {                                                                          \
        short8 pa = *reinterpret_cast<const short8*>(&P[w][l16][8 * lg]);      \
        _Pragma("unroll")                                                      \
        for (int cs = 0; cs < 4; ++cs) {                                       \
            short8 vb = *reinterpret_cast<const short8*>(                      \
                &vts[w][cs * 16 + l16][jo]);                                   \
            x1[cs] = __builtin_amdgcn_mfma_f32_16x16x32_bf16(pa, vb, x1[cs], 0, 0, 0); \
        }                                                                      \
    }                                                                          \
    _Pragma("unroll")                                                          \
    for (int il = 0; il < 2; ++il) {                                           \
        int i = 2 * w + il;                                                    \
        short8 pa2 = *reinterpret_cast<const short8*>(&P[l16 & 7][i][8 * lg]); \
        _Pragma("unroll")                                                      \
        for (int cg = 0; cg < 4; ++cg) {                                       \
            short8 bb;                                                         \
            _Pragma("unroll")                                                  \
            for (int e = 0; e < 8; ++e)                                        \
                bb[e] = (short)rpb_s[CUR][i][ro + e][cg * 16 + l16];           \
            x2[il][cg] = __builtin_amdgcn_mfma_f32_16x16x32_bf16(pa2, bb, x2[il][cg], 0, 0, 0); \
        }                                                                      \
    }
#endif

    for (int th = 0; th < 16; ++th) {
        ATTN_ITER(2 * th,     pfA, kpfA, vpfA, pfB, kpfB, vpfB)
        ATTN_ITER(2 * th + 1, pfB, kpfB, vpfB, pfA, kpfA, vpfA)
    }

    #pragma unroll
    for (int r = 0; r < 4; ++r) {
        float v = lsum[r];
        v += __shfl_xor(v, 1, 64); v += __shfl_xor(v, 2, 64);
        v += __shfl_xor(v, 4, 64); v += __shfl_xor(v, 8, 64);
        lsum[r] = v;
    }

    __syncthreads();
    float* x2s = reinterpret_cast<float*>(&rpb_s[0][0][0][0]);  // [16i][8h][64c]
    if (lg < 2) {
        #pragma unroll
        for (int il = 0; il < 2; ++il)
            #pragma unroll
            for (int cg = 0; cg < 4; ++cg)
                #pragma unroll
                for (int r = 0; r < 4; ++r)
                    x2s[((2 * w + il) * 8 + 4 * lg + r) * 64 + cg * 16 + l16] =
                        x2[il][cg][r];
    }
    __syncthreads();

    #pragma unroll
    for (int cs = 0; cs < 4; ++cs)
        #pragma unroll
        for (int r = 0; r < 4; ++r) {
            int ir = lg * 4 + r;
            float val = x1[cs][r] + x2s[(ir * 8 + w) * 64 + cs * 16 + l16];
            xpart[((size_t)js << 20) + ((size_t)(b * 1024 + i0 + ir)) * 512
                  + w * 64 + cs * 16 + l16] = val;
        }
    if (l16 == 0) {
        #pragma unroll
        for (int r = 0; r < 4; ++r)
            lsump[((size_t)js << 14) + (b * 8 + w) * 1024 + i0 + lg * 4 + r] = lsum[r];
    }
#undef ATTN_ITER
#undef X1X2_BODY
#undef RPB_ISSUE
#undef RPB_WRITE
#undef KH_ISSUE
#undef KH_WRITE
#undef VT_ISSUE
#undef VT_WRITE
}

// ---------------------------------------------------------------------------
__global__ __launch_bounds__(256) void combine(
    const float* __restrict__ xpart, const float* __restrict__ lsump,
    float* __restrict__ xb)
{
    int idx4 = blockIdx.x * 256 + threadIdx.x;
    size_t base = (size_t)idx4 * 4;
    int row = (int)(base >> 9), col = (int)(base & 511);
    int bb = row >> 10, n = row & 1023, h = col >> 6;
    float ax = 0.f, ay = 0.f, az = 0.f, aw = 0.f, ls = 0.f;
    #pragma unroll
    for (int js = 0; js < 2; ++js) {
        float4 v = *reinterpret_cast<const float4*>(xpart + ((size_t)js << 20) + base);
        ax += v.x; ay += v.y; az += v.z; aw += v.w;
        ls += lsump[(js << 14) + (bb * 8 + h) * 1024 + n];
    }
    float inv = 1.f / ls;
    float4 o; o.x = ax * inv; o.y = ay * inv; o.z = az * inv; o.w = aw * inv;
    *reinterpret_cast<float4*>(xb + base) = o;
}

// ---------------------------------------------------------------------------
extern "C" void kernel_launch(void* const* d_in, const int* in_sizes, int n_in,
                              void* d_out, int out_size, void* d_ws, size_t ws_size,
                              hipStream_t stream)
{
    (void)in_sizes; (void)n_in; (void)out_size; (void)ws_size;
    const float* q    = (const float*)d_in[0];
    const float* k    = (const float*)d_in[1];
    const float* v    = (const float*)d_in[2];
    const float* rpb  = (const float*)d_in[3];
    const float* mask = (const float*)d_in[4];
    const float* Wq   = (const float*)d_in[5];
    const float* Wk   = (const float*)d_in[6];
    const float* Wv   = (const float*)d_in[7];
    const float* Wp   = (const float*)d_in[8];
    const float* bp   = (const float*)d_in[9];
    float* out = (float*)d_out;

    unsigned short* qhb = (unsigned short*)d_ws;     // bf16 [2,8,1024,64]
    unsigned short* khb = qhb + 1048576;
    unsigned short* vtb = khb + 1048576;             // bf16 [2,8,64,1024]
    float* xpart = (float*)(vtb + 1048576);          // [2][2048][512]
    float* lsump = xpart + 2097152;                  // [2][16384]
    float* xb    = lsump + 32768;                    // [2048][512]
    unsigned short* wT = (unsigned short*)(xb + 1048576);  // bf16 [3][512n][512k]

    wprep<<<dim3(8, 8, 3), 256, 0, stream>>>(Wq, Wk, Wv, wT);

    proj_mfma<<<dim3(32, 8, 3), 256, 0, stream>>>(q, k, v, wT, qhb, khb, vtb);

    attn_mfma<<<256, 512, 0, stream>>>(qhb, khb, vtb, rpb, mask, xpart, lsump);

    combine<<<1024, 256, 0, stream>>>(xpart, lsump, xb);

    gemm512<1><<<dim3(32, 8, 1), 256, 0, stream>>>(xb, Wp, bp, out, nullptr, 1.0f);
}

// Round 15
// 185.057 us; speedup vs baseline: 1.4991x; 1.0222x over previous
//
#include <hip/hip_runtime.h>
#include <hip/hip_bf16.h>

// RelativeAttention B=2,N=1024,C=512,H=8,HD=64 — round 14: fused MFMA epilogue.
//  attn + proj_mfma = round-13 VERBATIM (189.2us total).
//  NEW: out_mfma replaces combine + f32 gemm512: A-staging fuses the jsplit
//  combine + 1/lsum normalize; GEMM runs bf16x3 (x=xh+xl, W=wh+wl, 3 MFMAs,
//  dropped xl*wl ~ 2^-18) for f32-grade precision at MFMA speed; bias fused.
//  wprep gains z=3: Wp -> WPhi/WPlo exact residual split (transposed).
//  Dispatches 5 -> 4.
// ws: qh 2MB | kh 2MB | vhT 2MB | xpart 8MB | lsum 128KB | WT 2.5MB

typedef __attribute__((ext_vector_type(8))) short short8;
typedef __attribute__((ext_vector_type(4))) short short4v;
typedef __attribute__((ext_vector_type(4))) float f32x4;

#if defined(__has_builtin)
#  if __has_builtin(__builtin_amdgcn_mfma_f32_16x16x16bf16_1k)
#    define HAVE_MFMA16 1
#  endif
#endif
#ifndef HAVE_MFMA16
#  define HAVE_MFMA16 0
#endif

__device__ __forceinline__ unsigned short f2b(float f) {
    union { float f; unsigned u; } v; v.f = f;
    unsigned r = (v.u + 0x7FFF + ((v.u >> 16) & 1)) >> 16;   // RNE
    return (unsigned short)r;
}
__device__ __forceinline__ float b2f(unsigned short h) {
    union { unsigned u; float f; } v; v.u = ((unsigned)h) << 16;
    return v.f;
}

__device__ __forceinline__ unsigned cvt_pk(float a, float b) {
    unsigned r;
    asm("v_cvt_pk_bf16_f32 %0, %1, %2" : "=v"(r) : "v"(a), "v"(b));
    return r;
}

// lgkm-drain + raw barrier: LDS ordered; global loads NOT drained.
#define LGKM0_BAR()                                            \
    do {                                                       \
        asm volatile("s_waitcnt lgkmcnt(0)" ::: "memory");     \
        __builtin_amdgcn_s_barrier();                          \
        asm volatile("" ::: "memory");                         \
    } while (0)

// ---------------------------------------------------------------------------
// wprep: W f32 [k][n] -> WT bf16 [n][k]. z=0..2: Wq/Wk/Wv. z=3: Wp -> hi+lo.
// ---------------------------------------------------------------------------
__global__ __launch_bounds__(256) void wprep(
    const float* __restrict__ W0, const float* __restrict__ W1,
    const float* __restrict__ W2, const float* __restrict__ W3,
    unsigned short* __restrict__ WT)
{
    const int z = blockIdx.z;
    const float* W = (z == 0) ? W0 : ((z == 1) ? W1 : ((z == 2) ? W2 : W3));
    __shared__ float Ts[64][65];
    const int t = threadIdx.x;
    const int k0 = blockIdx.x * 64, n0 = blockIdx.y * 64;
    const int kr = t >> 2, nc = (t & 3) * 16;
    #pragma unroll
    for (int q = 0; q < 4; ++q) {
        float4 v = *reinterpret_cast<const float4*>(
            W + (size_t)(k0 + kr) * 512 + n0 + nc + q * 4);
        Ts[kr][nc + q * 4 + 0] = v.x; Ts[kr][nc + q * 4 + 1] = v.y;
        Ts[kr][nc + q * 4 + 2] = v.z; Ts[kr][nc + q * 4 + 3] = v.w;
    }
    __syncthreads();
    const int nl = t >> 2, kc = (t & 3) * 16;
    if (z < 3) {
        unsigned short* T = WT + (size_t)z * 262144;
        unsigned short tmp[16];
        #pragma unroll
        for (int e = 0; e < 16; ++e) tmp[e] = f2b(Ts[kc + e][nl]);
        unsigned short* dst = T + (size_t)(n0 + nl) * 512 + k0 + kc;
        *reinterpret_cast<short8*>(dst)     = *reinterpret_cast<short8*>(&tmp[0]);
        *reinterpret_cast<short8*>(dst + 8) = *reinterpret_cast<short8*>(&tmp[8]);
    } else {
        unsigned short* Th = WT + (size_t)3 * 262144;
        unsigned short* Tl = WT + (size_t)4 * 262144;
        unsigned short hi[16], lo[16];
        #pragma unroll
        for (int e = 0; e < 16; ++e) {
            float v = Ts[kc + e][nl];
            hi[e] = f2b(v);
            lo[e] = f2b(v - b2f(hi[e]));
        }
        unsigned short* dh = Th + (size_t)(n0 + nl) * 512 + k0 + kc;
        unsigned short* dl = Tl + (size_t)(n0 + nl) * 512 + k0 + kc;
        *reinterpret_cast<short8*>(dh)     = *reinterpret_cast<short8*>(&hi[0]);
        *reinterpret_cast<short8*>(dh + 8) = *reinterpret_cast<short8*>(&hi[8]);
        *reinterpret_cast<short8*>(dl)     = *reinterpret_cast<short8*>(&lo[0]);
        *reinterpret_cast<short8*>(dl + 8) = *reinterpret_cast<short8*>(&lo[8]);
    }
}

// ---------------------------------------------------------------------------
// proj_mfma: round-13 VERBATIM. grid (32,8,3), 256 thr.
// ---------------------------------------------------------------------------
__global__ __launch_bounds__(256) void proj_mfma(
    const float* __restrict__ qg, const float* __restrict__ kg,
    const float* __restrict__ vg, const unsigned short* __restrict__ WT,
    unsigned short* __restrict__ qhb, unsigned short* __restrict__ khb,
    unsigned short* __restrict__ vtb)
{
    const int z = blockIdx.z;
    const float* X = (z == 0) ? qg : ((z == 1) ? kg : vg);
    const unsigned short* WTz = WT + (size_t)z * 262144;
    const float scale = (z == 0) ? 0.125f : 1.0f;

    __shared__ unsigned short As[64][72];
    const int t = threadIdx.x, w = t >> 6, l = t & 63;
    const int l16 = l & 15, lg = l >> 4;
    const int m0 = blockIdx.x * 64, n0 = blockIdx.y * 64;
    const int ra = t >> 2, kc = (t & 3) * 16;

    f32x4 acc[4];
    #pragma unroll
    for (int cs = 0; cs < 4; ++cs) acc[cs] = 0.0f;

    for (int k0 = 0; k0 < 512; k0 += 64) {
        float4 va[4];
        #pragma unroll
        for (int qq = 0; qq < 4; ++qq)
            va[qq] = *reinterpret_cast<const float4*>(
                X + (size_t)(m0 + ra) * 512 + k0 + kc + qq * 4);
        uint4 pk0, pk1;
        pk0.x = cvt_pk(va[0].x, va[0].y); pk0.y = cvt_pk(va[0].z, va[0].w);
        pk0.z = cvt_pk(va[1].x, va[1].y); pk0.w = cvt_pk(va[1].z, va[1].w);
        pk1.x = cvt_pk(va[2].x, va[2].y); pk1.y = cvt_pk(va[2].z, va[2].w);
        pk1.z = cvt_pk(va[3].x, va[3].y); pk1.w = cvt_pk(va[3].z, va[3].w);
        __syncthreads();
        *reinterpret_cast<uint4*>(&As[ra][kc])     = pk0;
        *reinterpret_cast<uint4*>(&As[ra][kc + 8]) = pk1;
        __syncthreads();
        #pragma unroll
        for (int kk = 0; kk < 2; ++kk) {
            short8 a = *reinterpret_cast<const short8*>(
                &As[w * 16 + l16][kk * 32 + 8 * lg]);
            #pragma unroll
            for (int cs = 0; cs < 4; ++cs) {
                short8 b = *reinterpret_cast<const short8*>(
                    WTz + (size_t)(n0 + cs * 16 + l16) * 512 + k0 + kk * 32 + 8 * lg);
                acc[cs] = __builtin_amdgcn_mfma_f32_16x16x32_bf16(a, b, acc[cs], 0, 0, 0);
            }
        }
    }

    const int h = blockIdx.y;
    if (z < 2) {
        unsigned short* Y = (z == 0) ? qhb : khb;
        #pragma unroll
        for (int cs = 0; cs < 4; ++cs)
            #pragma unroll
            for (int r = 0; r < 4; ++r) {
                int m = m0 + w * 16 + lg * 4 + r;
                int bb = m >> 10, nn = m & 1023;
                Y[(((size_t)((bb * 8 + h) * 1024 + nn)) << 6) + cs * 16 + l16] =
                    f2b(acc[cs][r] * scale);
            }
    } else {
        int mbase = m0 + w * 16 + lg * 4;
        int bb = mbase >> 10, nn = mbase & 1023;
        #pragma unroll
        for (int cs = 0; cs < 4; ++cs) {
            ushort4 o;
            o.x = f2b(acc[cs][0]); o.y = f2b(acc[cs][1]);
            o.z = f2b(acc[cs][2]); o.w = f2b(acc[cs][3]);
            *reinterpret_cast<ushort4*>(
                vtb + (((size_t)(bb * 8 + h) * 64 + cs * 16 + l16) << 10) + nn) = o;
        }
    }
}

// ---------------------------------------------------------------------------
// out_mfma: out = ((xpart0+xpart1)/lsum) @ Wp + bp, bf16x3 split MFMA.
// grid (32, 8), 256 thr = 4 waves.
// ---------------------------------------------------------------------------
__global__ __launch_bounds__(256) void out_mfma(
    const float* __restrict__ xpart, const float* __restrict__ lsump,
    const unsigned short* __restrict__ WT, const float* __restrict__ bp,
    float* __restrict__ out)
{
    const unsigned short* WPhi = WT + (size_t)3 * 262144;
    const unsigned short* WPlo = WT + (size_t)4 * 262144;
    __shared__ unsigned short Ah[64][72];
    __shared__ unsigned short Al[64][72];
    const int t = threadIdx.x, w = t >> 6, l = t & 63;
    const int l16 = l & 15, lg = l >> 4;
    const int m0 = blockIdx.x * 64, n0 = blockIdx.y * 64;
    const int ra = t >> 2, kc = (t & 3) * 16;
    const int mrow = m0 + ra, bb = mrow >> 10, nn = mrow & 1023;

    f32x4 acc[4];
    #pragma unroll
    for (int cs = 0; cs < 4; ++cs) acc[cs] = 0.0f;

    for (int k0 = 0; k0 < 512; k0 += 64) {
        const int h = k0 >> 6;   // head is constant across the K-tile
        float ls = lsump[(bb * 8 + h) * 1024 + nn]
                 + lsump[16384 + (bb * 8 + h) * 1024 + nn];
        float inv = 1.0f / ls;
        unsigned short hi[16], lo[16];
        #pragma unroll
        for (int qq = 0; qq < 4; ++qq) {
            size_t base = ((size_t)(bb * 1024 + nn)) * 512 + k0 + kc + qq * 4;
            float4 v0 = *reinterpret_cast<const float4*>(xpart + base);
            float4 v1 = *reinterpret_cast<const float4*>(xpart + (1u << 20) + base);
            float e0 = (v0.x + v1.x) * inv, e1 = (v0.y + v1.y) * inv;
            float e2 = (v0.z + v1.z) * inv, e3 = (v0.w + v1.w) * inv;
            hi[qq * 4 + 0] = f2b(e0); lo[qq * 4 + 0] = f2b(e0 - b2f(hi[qq * 4 + 0]));
            hi[qq * 4 + 1] = f2b(e1); lo[qq * 4 + 1] = f2b(e1 - b2f(hi[qq * 4 + 1]));
            hi[qq * 4 + 2] = f2b(e2); lo[qq * 4 + 2] = f2b(e2 - b2f(hi[qq * 4 + 2]));
            hi[qq * 4 + 3] = f2b(e3); lo[qq * 4 + 3] = f2b(e3 - b2f(hi[qq * 4 + 3]));
        }
        __syncthreads();
        *reinterpret_cast<short8*>(&Ah[ra][kc])     = *reinterpret_cast<short8*>(&hi[0]);
        *reinterpret_cast<short8*>(&Ah[ra][kc + 8]) = *reinterpret_cast<short8*>(&hi[8]);
        *reinterpret_cast<short8*>(&Al[ra][kc])     = *reinterpret_cast<short8*>(&lo[0]);
        *reinterpret_cast<short8*>(&Al[ra][kc + 8]) = *reinterpret_cast<short8*>(&lo[8]);
        __syncthreads();
        #pragma unroll
        for (int kk = 0; kk < 2; ++kk) {
            short8 ah = *reinterpret_cast<const short8*>(
                &Ah[w * 16 + l16][kk * 32 + 8 * lg]);
            short8 al = *reinterpret_cast<const short8*>(
                &Al[w * 16 + l16][kk * 32 + 8 * lg]);
            #pragma unroll
            for (int cs = 0; cs < 4; ++cs) {
                size_t wb = (size_t)(n0 + cs * 16 + l16) * 512 + k0 + kk * 32 + 8 * lg;
                short8 bh = *reinterpret_cast<const short8*>(WPhi + wb);
                short8 bl = *reinterpret_cast<const short8*>(WPlo + wb);
                acc[cs] = __builtin_amdgcn_mfma_f32_16x16x32_bf16(ah, bh, acc[cs], 0, 0, 0);
                acc[cs] = __builtin_amdgcn_mfma_f32_16x16x32_bf16(ah, bl, acc[cs], 0, 0, 0);
                acc[cs] = __builtin_amdgcn_mfma_f32_16x16x32_bf16(al, bh, acc[cs], 0, 0, 0);
            }
        }
    }

    #pragma unroll
    for (int cs = 0; cs < 4; ++cs) {
        int col = n0 + cs * 16 + l16;
        float bv = bp[col];
        #pragma unroll
        for (int r = 0; r < 4; ++r) {
            int row = m0 + w * 16 + lg * 4 + r;
            out[(size_t)row * 512 + col] = acc[cs][r] + bv;
        }
    }
}

// ---------------------------------------------------------------------------
// attn: round-11/13 kernel VERBATIM.
// grid 256 = b(2) x itile(64) x jsplit(2); 512 thr = 8 waves = heads
// ---------------------------------------------------------------------------
__global__ __launch_bounds__(512, 2) void attn_mfma(
    const unsigned short* __restrict__ qhg, const unsigned short* __restrict__ khg,
    const unsigned short* __restrict__ vtg, const float* __restrict__ rpb,
    const float* __restrict__ mask, float* __restrict__ xpart,
    float* __restrict__ lsump)
{
    __shared__ unsigned short rpb_s[2][16][16][72]; // dbuf rpb tile   73728B
    __shared__ unsigned short khs[8][16][72];       // kh tile [h][j][c] 18432B
    __shared__ unsigned short vts[8][64][24];       // vt tile [h][c][j] 24576B
    __shared__ unsigned short q1[8][16][72];        // prologue q       18432B
    __shared__ unsigned short P[8][16][40];         // j16..39 ZERO     10240B
    __shared__ float S2s[16][8][17];                //                   8704B
    __shared__ float mask_s[512];                   //                   2048B

    const int bid = blockIdx.x;
    const int js = bid & 1, it = (bid >> 1) & 63, b = bid >> 7;
    const int i0 = it * 16, jb = js * 512;
    const int t = threadIdx.x, w = t >> 6, l = t & 63;
    const int lg = l >> 4, l16 = l & 15;

    const int sj = (t >> 3) & 15, sc = (t & 7) * 8, sib = t >> 7;
    const int kh_h = t >> 6, kh_j = (t >> 2) & 15, kh_c = (t & 3) * 16;
    const int vt_h = t >> 6, vt_c = t & 63;

    const float* rpbb = rpb + ((size_t)(b * 1024 + i0) << 16);

#define RPB_ISSUE(PF, J0)                                                      \
    _Pragma("unroll")                                                          \
    for (int itr = 0; itr < 4; ++itr) {                                        \
        const float4* s_ = reinterpret_cast<const float4*>(                    \
            rpbb + ((size_t)(sib + 4 * itr) << 16) +                           \
            (size_t)((J0) + sj) * 64 + sc);                                    \
        PF[2 * itr] = s_[0]; PF[2 * itr + 1] = s_[1];                          \
    }

#define RPB_WRITE(PF, BUF)                                                     \
    _Pragma("unroll")                                                          \
    for (int itr = 0; itr < 4; ++itr) {                                        \
        float4 ua = PF[2 * itr], ub = PF[2 * itr + 1];                         \
        uint4 pk;                                                              \
        pk.x = cvt_pk(ua.x, ua.y); pk.y = cvt_pk(ua.z, ua.w);                  \
        pk.z = cvt_pk(ub.x, ub.y); pk.w = cvt_pk(ub.z, ub.w);                  \
        *reinterpret_cast<uint4*>(&rpb_s[BUF][sib + 4 * itr][sj][sc]) = pk;    \
    }

#define KH_ISSUE(KP, J0)                                                       \
    {                                                                          \
        const unsigned short* p_ = khg + ((size_t)(b * 8 + kh_h) << 16) +      \
            (size_t)((J0) + kh_j) * 64 + kh_c;                                 \
        KP[0] = *reinterpret_cast<const short8*>(p_);                          \
        KP[1] = *reinterpret_cast<const short8*>(p_ + 8);                      \
    }

#define KH_WRITE(KP)                                                           \
    {                                                                          \
        *reinterpret_cast<short8*>(&khs[kh_h][kh_j][kh_c])     = KP[0];        \
        *reinterpret_cast<short8*>(&khs[kh_h][kh_j][kh_c + 8]) = KP[1];        \
    }

#define VT_ISSUE(VP, J0)                                                       \
    {                                                                          \
        const unsigned short* p_ = vtg + ((size_t)(b * 8 + vt_h) << 16) +      \
            ((size_t)vt_c << 10) + (J0);                                       \
        VP[0] = *reinterpret_cast<const short8*>(p_);                          \
        VP[1] = *reinterpret_cast<const short8*>(p_ + 8);                      \
    }

#define VT_WRITE(VP)                                                           \
    {                                                                          \
        *reinterpret_cast<short8*>(&vts[vt_h][vt_c][0]) = VP[0];               \
        *reinterpret_cast<short8*>(&vts[vt_h][vt_c][8]) = VP[1];               \
    }

    {
        int h = t >> 6, i = (t >> 2) & 15, c = (t & 3) * 16;
        const short8* src = reinterpret_cast<const short8*>(
            qhg + (((size_t)(b * 8 + h) * 1024 + i0 + i) << 6) + c);
        *reinterpret_cast<short8*>(&q1[h][i][c])     = src[0];
        *reinterpret_cast<short8*>(&q1[h][i][c + 8]) = src[1];
    }
    if (t < 128) {
        *reinterpret_cast<float4*>(&mask_s[t * 4]) =
            *reinterpret_cast<const float4*>(&mask[b * 1024 + jb + t * 4]);
    }
    {
        unsigned short* P1 = &P[0][0][0];
        #pragma unroll
        for (int r = 0; r < 10; ++r) P1[t + 512 * r] = 0;   // 5120 = 512*10
    }
    float mrow[4];
    #pragma unroll
    for (int r = 0; r < 4; r++) mrow[r] = mask[b * 1024 + i0 + lg * 4 + r];

    float4 pfA[8], pfB[8];
    short8 kpfA[2], kpfB[2], vpfA[2], vpfB[2];
    RPB_ISSUE(pfA, jb)
    KH_ISSUE(kpfA, jb)
    VT_ISSUE(vpfA, jb)

    LGKM0_BAR();

    short8 a1[2];
    a1[0] = *reinterpret_cast<const short8*>(&q1[w][l16][8 * lg]);
    a1[1] = *reinterpret_cast<const short8*>(&q1[w][l16][32 + 8 * lg]);
    short8 bq[2][2];
    #pragma unroll
    for (int il = 0; il < 2; ++il) {
        bq[il][0] = *reinterpret_cast<const short8*>(
            &q1[l16 & 7][2 * w + il][8 * lg]);
        bq[il][1] = *reinterpret_cast<const short8*>(
            &q1[l16 & 7][2 * w + il][32 + 8 * lg]);
    }

    const int jo = (lg < 2) ? 8 * lg : 0;
    const int ro = jo;
    (void)ro;

    f32x4 x1[4];
    #pragma unroll
    for (int cs = 0; cs < 4; cs++) x1[cs] = 0.0f;
    f32x4 x2[2][4];
    #pragma unroll
    for (int il = 0; il < 2; il++)
        #pragma unroll
        for (int cg = 0; cg < 4; cg++) x2[il][cg] = 0.0f;
    float lsum[4] = {0.f, 0.f, 0.f, 0.f};

#define ATTN_ITER(T, PFC, KPC, VPC, PFN, KPN, VPN)                             \
    {                                                                          \
        const int jt = (T);                                                    \
        const int cur = jt & 1;                                                \
        const int j0 = jb + jt * 16;                                           \
        if (jt < 31) {                                                         \
            RPB_ISSUE(PFN, j0 + 16)                                            \
            KH_ISSUE(KPN, j0 + 16)                                             \
            VT_ISSUE(VPN, j0 + 16)                                             \
        }                                                                      \
        RPB_WRITE(PFC, cur)                                                    \
        KH_WRITE(KPC)                                                          \
        VT_WRITE(VPC)                                                          \
        LGKM0_BAR();                                                           \
        f32x4 C1; C1 = 0.0f;                                                   \
        {                                                                      \
            short8 kb0 = *reinterpret_cast<const short8*>(&khs[w][l16][8 * lg]); \
            short8 kb1 = *reinterpret_cast<const short8*>(&khs[w][l16][32 + 8 * lg]); \
            C1 = __builtin_amdgcn_mfma_f32_16x16x32_bf16(a1[0], kb0, C1, 0, 0, 0); \
            C1 = __builtin_amdgcn_mfma_f32_16x16x32_bf16(a1[1], kb1, C1, 0, 0, 0); \
        }                                                                      \
        _Pragma("unroll")                                                      \
        for (int il = 0; il < 2; ++il) {                                       \
            int i = 2 * w + il;                                                \
            f32x4 D2; D2 = 0.0f;                                               \
            _Pragma("unroll")                                                  \
            for (int ch = 0; ch < 2; ++ch) {                                   \
                short8 ar = *reinterpret_cast<const short8*>(                  \
                    &rpb_s[cur][i][l16][ch * 32 + 8 * lg]);                    \
                D2 = __builtin_amdgcn_mfma_f32_16x16x32_bf16(ar, bq[il][ch], D2, 0, 0, 0); \
            }                                                                  \
            if (l16 < 8) {                                                     \
                _Pragma("unroll")                                              \
                for (int r = 0; r < 4; ++r)                                    \
                    S2s[i][l16][4 * lg + r] = D2[r];                           \
            }                                                                  \
        }                                                                      \
        LGKM0_BAR();                                                           \
        {                                                                      \
            float mj = mask_s[jt * 16 + l16];                                  \
            _Pragma("unroll")                                                  \
            for (int r = 0; r < 4; ++r) {                                      \
                int ir = lg * 4 + r;                                           \
                float mi = mrow[r];                                            \
                float pm = (fmaxf(mi, mj) < 0.f) ? 0.f : fminf(mi, mj);        \
                float s = C1[r] + S2s[ir][w][l16] + pm;                        \
                float p = __expf(s);                                           \
                lsum[r] += p;                                                  \
                P[w][ir][l16] = f2b(p);                                        \
            }                                                                  \
        }                                                                      \
        LGKM0_BAR();                                                           \
        X1X2_BODY(cur)                                                         \
        LGKM0_BAR();                                                           \
    }

#if HAVE_MFMA16
#define X1X2_BODY(CUR)                                                         \
    {                                                                          \
        short4v pa = *reinterpret_cast<const short4v*>(&P[w][l16][4 * lg]);    \
        _Pragma("unroll")                                                      \
        for (int cs = 0; cs < 4; ++cs) {                                       \
            short4v vb = *reinterpret_cast<const short4v*>(                    \
                &vts[w][cs * 16 + l16][4 * lg]);                               \
            x1[cs] = __builtin_amdgcn_mfma_f32_16x16x16bf16_1k(pa, vb, x1[cs], 0, 0, 0); \
        }                                                                      \
    }                                                                          \
    _Pragma("unroll")                                                          \
    for (int il = 0; il < 2; ++il) {                                           \
        int i = 2 * w + il;                                                    \
        short4v pa2 = *reinterpret_cast<const short4v*>(&P[l16 & 7][i][4 * lg]); \
        _Pragma("unroll")                                                      \
        for (int cg = 0; cg < 4; ++cg) {                                       \
            short4v bb;                                                        \
            _Pragma("unroll")                                                  \
            for (int e = 0; e < 4; ++e)                                        \
                bb[e] = (short)rpb_s[CUR][i][4 * lg + e][cg * 16 + l16];       \
            x2[il][cg] = __builtin_amdgcn_mfma_f32_16x16x16bf16_1k(pa2, bb, x2[il][cg], 0, 0, 0); \
        }                                                                      \
    }
#else
#define X1X2_BODY(CUR)                                                         \
    {                                                                          \
        short8 pa = *reinterpret_cast<const short8*>(&P[w][l16][8 * lg]);      \
        _Pragma("unroll")                                                      \
        for (int cs = 0; cs < 4; ++cs) {                                       \
            short8 vb = *reinterpret_cast<const short8*>(                      \
                &vts[w][cs * 16 + l16][jo]);                                   \
            x1[cs] = __builtin_amdgcn_mfma_f32_16x16x32_bf16(pa, vb, x1[cs], 0, 0, 0); \
        }                                                                      \
    }                                                                          \
    _Pragma("unroll")                                                          \
    for (int il = 0; il < 2; ++il) {                                           \
        int i = 2 * w + il;                                                    \
        short8 pa2 = *reinterpret_cast<const short8*>(&P[l16 & 7][i][8 * lg]); \
        _Pragma("unroll")                                                      \
        for (int cg = 0; cg < 4; ++cg) {                                       \
            short8 bb;                                                         \
            _Pragma("unroll")                                                  \
            for (int e = 0; e < 8; ++e)                                        \
                bb[e] = (short)rpb_s[CUR][i][ro + e][cg * 16 + l16];           \
            x2[il][cg] = __builtin_amdgcn_mfma_f32_16x16x32_bf16(pa2, bb, x2[il][cg], 0, 0, 0); \
        }                                                                      \
    }
#endif

    for (int th = 0; th < 16; ++th) {
        ATTN_ITER(2 * th,     pfA, kpfA, vpfA, pfB, kpfB, vpfB)
        ATTN_ITER(2 * th + 1, pfB, kpfB, vpfB, pfA, kpfA, vpfA)
    }

    #pragma unroll
    for (int r = 0; r < 4; ++r) {
        float v = lsum[r];
        v += __shfl_xor(v, 1, 64); v += __shfl_xor(v, 2, 64);
        v += __shfl_xor(v, 4, 64); v += __shfl_xor(v, 8, 64);
        lsum[r] = v;
    }

    __syncthreads();
    float* x2s = reinterpret_cast<float*>(&rpb_s[0][0][0][0]);  // [16i][8h][64c]
    if (lg < 2) {
        #pragma unroll
        for (int il = 0; il < 2; ++il)
            #pragma unroll
            for (int cg = 0; cg < 4; ++cg)
                #pragma unroll
                for (int r = 0; r < 4; ++r)
                    x2s[((2 * w + il) * 8 + 4 * lg + r) * 64 + cg * 16 + l16] =
                        x2[il][cg][r];
    }
    __syncthreads();

    #pragma unroll
    for (int cs = 0; cs < 4; ++cs)
        #pragma unroll
        for (int r = 0; r < 4; ++r) {
            int ir = lg * 4 + r;
            float val = x1[cs][r] + x2s[(ir * 8 + w) * 64 + cs * 16 + l16];
            xpart[((size_t)js << 20) + ((size_t)(b * 1024 + i0 + ir)) * 512
                  + w * 64 + cs * 16 + l16] = val;
        }
    if (l16 == 0) {
        #pragma unroll
        for (int r = 0; r < 4; ++r)
            lsump[((size_t)js << 14) + (b * 8 + w) * 1024 + i0 + lg * 4 + r] = lsum[r];
    }
#undef ATTN_ITER
#undef X1X2_BODY
#undef RPB_ISSUE
#undef RPB_WRITE
#undef KH_ISSUE
#undef KH_WRITE
#undef VT_ISSUE
#undef VT_WRITE
}

// ---------------------------------------------------------------------------
extern "C" void kernel_launch(void* const* d_in, const int* in_sizes, int n_in,
                              void* d_out, int out_size, void* d_ws, size_t ws_size,
                              hipStream_t stream)
{
    (void)in_sizes; (void)n_in; (void)out_size; (void)ws_size;
    const float* q    = (const float*)d_in[0];
    const float* k    = (const float*)d_in[1];
    const float* v    = (const float*)d_in[2];
    const float* rpb  = (const float*)d_in[3];
    const float* mask = (const float*)d_in[4];
    const float* Wq   = (const float*)d_in[5];
    const float* Wk   = (const float*)d_in[6];
    const float* Wv   = (const float*)d_in[7];
    const float* Wp   = (const float*)d_in[8];
    const float* bp   = (const float*)d_in[9];
    float* out = (float*)d_out;

    unsigned short* qhb = (unsigned short*)d_ws;     // bf16 [2,8,1024,64]
    unsigned short* khb = qhb + 1048576;
    unsigned short* vtb = khb + 1048576;             // bf16 [2,8,64,1024]
    float* xpart = (float*)(vtb + 1048576);          // [2][2048][512]
    float* lsump = xpart + 2097152;                  // [2][16384]
    unsigned short* wT = (unsigned short*)(lsump + 32768); // bf16 [5][512][512]

    wprep<<<dim3(8, 8, 4), 256, 0, stream>>>(Wq, Wk, Wv, Wp, wT);

    proj_mfma<<<dim3(32, 8, 3), 256, 0, stream>>>(q, k, v, wT, qhb, khb, vtb);

    attn_mfma<<<256, 512, 0, stream>>>(qhb, khb, vtb, rpb, mask, xpart, lsump);

    out_mfma<<<dim3(32, 8), 256, 0, stream>>>(xpart, lsump, wT, bp, out);
}